// Round 15
// baseline (44.417 us; speedup 1.0000x reference)
//
#include <hip/hip_runtime.h>
#include <math.h>

// Bit-match the verified reference fp32 pipeline (rounds 4-14, absmax=0):
//   dot = ascending single-accumulator FMA chain over c=0..3
//   d   = (x2 - 2*dot) + e2, single roundings, strict-< first-occurrence argmin.
// -2 folded into registers: e' = -2e exact; chain(x,e') == -2*dot bitwise;
// (x2 + dot') + e2 == reference (verified r14, absmax=0).
//
// STRUCTURE (new): codes live in REGISTERS, not LDS. Lane l owns 32 codes
// c = j*64+l (coalesced load). Rows stream past as wave-uniform x loads.
// Hot loop has ZERO ds_read — this removes the uniform-LDS streaming that
// every 25-28us variant (r8-r14) shared. Cross-lane argmin reduce via
// shfl_xor (swizzle, no LDS alloc), integer-min on global indices preserves
// np.argmin first-occurrence exactly.
#pragma clang fp contract(off)

constexpr int KCODES = 2048;   // EMBEDDING_LENGTH
constexpr int CDIM   = 4;      // EMBEDDING_DIM
constexpr int CPL    = 32;     // codes per lane (64 lanes x 32 = 2048)
constexpr int ROWSPW = 32;     // rows per wave
constexpr int WPB    = 8;      // waves per block (512 threads)

__device__ __forceinline__ float min3f(float a, float b, float c) {
    float d; asm("v_min3_f32 %0, %1, %2, %3" : "=v"(d) : "v"(a), "v"(b), "v"(c)); return d;
}

__global__ __launch_bounds__(512, 2) void vq_reg(
    const float* __restrict__ x,
    const float* __restrict__ emb,
    int* __restrict__ out,
    int N)
{
    const float4* __restrict__ embf4 = reinterpret_cast<const float4*>(emb);
    const float4* __restrict__ xf4   = reinterpret_cast<const float4*>(x);

    const int t    = threadIdx.x;
    const int lane = t & 63;
    const int wid  = __builtin_amdgcn_readfirstlane(t >> 6);   // r6 lesson
    const int gw   = blockIdx.x * WPB + wid;                   // global wave
    const int rowbase = gw * ROWSPW;

    // ---- one-time: load 32 codes per lane into registers (coalesced:
    // iteration j reads codes j*64 + lane). e' = -2e (exact); s = sumsq(e)
    // with the reference's ascending unfused mul-add.
    float e0[CPL], e1[CPL], e2v[CPL], e3[CPL], sv[CPL];
    #pragma unroll
    for (int j = 0; j < CPL; ++j) {
        const float4 e = embf4[j * 64 + lane];
        sv[j]  = ((e.x * e.x + e.y * e.y) + e.z * e.z) + e.w * e.w;
        e0[j]  = -2.0f * e.x;
        e1[j]  = -2.0f * e.y;
        e2v[j] = -2.0f * e.z;
        e3[j]  = -2.0f * e.w;
    }

    // ---- rows stream past the register-resident codebook ----
    float4 xnext = xf4[min(rowbase, N - 1)];   // wave-uniform prefetch
    for (int r = 0; r < ROWSPW; ++r) {
        const int n = rowbase + r;
        if (n >= N) break;
        const float4 xv = xnext;
        xnext = xf4[min(n + 1, N - 1)];        // prefetch next row (uniform)

        const float xs = ((xv.x * xv.x + xv.y * xv.y)
                          + xv.z * xv.z) + xv.w * xv.w;

        // per-lane scan of 16 code pairs; track (dmin, winning pair bp,
        // de of winning pair). Strict <: earliest pair kept on ties.
        float dmin = HUGE_VALF;
        float dew  = HUGE_VALF;
        int   bp   = 0;
        #pragma unroll
        for (int p = 0; p < CPL / 2; ++p) {
            const int je = 2 * p, jo = 2 * p + 1;
            float dt = xv.x * e0[je];
            dt = __builtin_fmaf(xv.y, e1[je], dt);
            dt = __builtin_fmaf(xv.z, e2v[je], dt);
            dt = __builtin_fmaf(xv.w, e3[je], dt);
            const float de = (xs + dt) + sv[je];
            float du = xv.x * e0[jo];
            du = __builtin_fmaf(xv.y, e1[jo], du);
            du = __builtin_fmaf(xv.z, e2v[jo], du);
            du = __builtin_fmaf(xv.w, e3[jo], du);
            const float dodd = (xs + du) + sv[jo];

            const float nd = min3f(dmin, de, dodd);
            const bool  c  = nd < dmin;
            bp   = c ? p : bp;
            dew  = c ? de : dew;
            dmin = nd;
        }
        // local winner: even wins exact within-pair ties (smaller index)
        const int jwin = 2 * bp + ((dew == dmin) ? 0 : 1);
        const int gidx = jwin * 64 + lane;     // global code index

        // cross-lane: exact f32 min, then smallest global index among ties
        float rm = dmin;
        #pragma unroll
        for (int m = 32; m >= 1; m >>= 1)
            rm = fminf(rm, __shfl_xor(rm, m));
        int cand = (dmin == rm) ? gidx : 0x7fffffff;
        #pragma unroll
        for (int m = 32; m >= 1; m >>= 1)
            cand = min(cand, __shfl_xor(cand, m));

        if (lane == 0) out[n] = cand;
    }
}

extern "C" void kernel_launch(void* const* d_in, const int* in_sizes, int n_in,
                              void* d_out, int out_size, void* d_ws, size_t ws_size,
                              hipStream_t stream) {
    const float* x   = (const float*)d_in[0];   // [16,64,64,4] -> [N,4]
    const float* emb = (const float*)d_in[1];   // [2048,4]
    int* out = (int*)d_out;                     // [N] int32
    const int N = in_sizes[0] / CDIM;           // 65536

    const int rows_per_block = WPB * ROWSPW;    // 256
    vq_reg<<<(N + rows_per_block - 1) / rows_per_block, 512, 0, stream>>>(
        x, emb, out, N);
}

// Round 16
// 28.275 us; speedup vs baseline: 1.5709x; 1.5709x over previous
//
#include <hip/hip_runtime.h>
#include <math.h>

// Bit-match the verified reference fp32 pipeline (rounds 4-14, absmax=0):
//   dot = ascending single-accumulator FMA chain
//   d   = (x2 - 2*dot) + e2, single roundings, strict-< first-occurrence argmin.
// -2 folded into the staged table (exact; verified r14).
// r16 change: SAME pipeline/DS-traffic as r14, but KSPLIT=16 with 1024-thread
// blocks -> 32 waves/CU (8/SIMD) instead of 16/CU. Tests whether the 28%
// VALUBusy stall gap (18us issue vs 25us wall) is un-hidden lgkm latency.
#pragma clang fp contract(off)

constexpr int KCODES = 2048;   // EMBEDDING_LENGTH
constexpr int CDIM   = 4;      // EMBEDDING_DIM
constexpr int KSPLIT = 16;     // one k-chunk per wave (16 waves/block)
constexpr int KCHUNK = KCODES / KSPLIT;  // 128 codes per wave
constexpr int RPT    = 2;      // rows per lane
constexpr int ROWSPB = 64 * RPT;         // 128 rows per block
constexpr int TPB    = 64 * KSPLIT;      // 1024 threads

__device__ __forceinline__ float min3f(float a, float b, float c) {
    float d; asm("v_min3_f32 %0, %1, %2, %3" : "=v"(d) : "v"(a), "v"(b), "v"(c)); return d;
}
__device__ __forceinline__ float sumsq(float4 e) {
    // np.sum(e*e, -1): ascending unfused mul-add (n<8 scalar loop)
    return ((e.x * e.x + e.y * e.y) + e.z * e.z) + e.w * e.w;
}

__global__ __launch_bounds__(TPB, 8) void vq_fused(
    const float* __restrict__ x,
    const float* __restrict__ emb,
    int* __restrict__ out,
    int N)
{
    __shared__ float4 sE[KCODES];       // 32 KB: e' = -2e per code
    __shared__ float4 sS[KCODES / 4];   //  8 KB: e2 sums, 4 codes per float4

    const float4* __restrict__ embf4 = reinterpret_cast<const float4*>(emb);
    const int t = threadIdx.x;

    for (int i = t; i < KCODES; i += TPB) {
        float4 e = embf4[i];
        sE[i] = make_float4(-2.0f * e.x, -2.0f * e.y, -2.0f * e.z, -2.0f * e.w);
    }
    for (int q = t; q < KCODES / 4; q += TPB) {
        float4 e0 = embf4[4 * q],     e1 = embf4[4 * q + 1];
        float4 e2 = embf4[4 * q + 2], e3 = embf4[4 * q + 3];
        sS[q] = make_float4(sumsq(e0), sumsq(e1), sumsq(e2), sumsq(e3));
    }
    __syncthreads();

    const int lane = t & 63;
    const int wid   = __builtin_amdgcn_readfirstlane(t >> 6);  // r6 lesson
    const int kbase = wid * KCHUNK;
    const int qbase = kbase >> 2;
    const int nbase = blockIdx.x * ROWSPB + lane;

    float x0[RPT], x1[RPT], x2c[RPT], x3[RPT], xs[RPT];
    float dmin[RPT];
    int   bg[RPT];
    #pragma unroll
    for (int r = 0; r < RPT; ++r) {
        const int n = nbase + r * 64;
        float4 xv = (n < N) ? reinterpret_cast<const float4*>(x)[n]
                            : make_float4(0.f, 0.f, 0.f, 0.f);
        x0[r] = xv.x; x1[r] = xv.y; x2c[r] = xv.z; x3[r] = xv.w;
        xs[r] = ((xv.x * xv.x + xv.y * xv.y) + xv.z * xv.z) + xv.w * xv.w;
        dmin[r] = HUGE_VALF; bg[r] = 0;
    }

    // 6 scalar VALU per code + 1 min3 per 2 codes + 2 tracking per group.
    #pragma unroll 2
    for (int g = 0; g < KCHUNK / 8; ++g) {   // 16 groups x 8 codes
        const int k0 = kbase + (g << 3);
        const float4 e0 = sE[k0 + 0], e1 = sE[k0 + 1];
        const float4 e2 = sE[k0 + 2], e3 = sE[k0 + 3];
        const float4 e4 = sE[k0 + 4], e5 = sE[k0 + 5];
        const float4 e6 = sE[k0 + 6], e7 = sE[k0 + 7];
        const float4 sA = sS[qbase + 2 * g];
        const float4 sB = sS[qbase + 2 * g + 1];

        #pragma unroll
        for (int r = 0; r < RPT; ++r) {
            const float a0 = x0[r], a1 = x1[r], a2 = x2c[r], a3 = x3[r];
            const float xq = xs[r];
            const float prev = dmin[r];

            #define VQ_D(EV, SV, OUTV)                                   \
                do {                                                     \
                    float dt = a0 * EV.x;                                \
                    dt = __builtin_fmaf(a1, EV.y, dt);                   \
                    dt = __builtin_fmaf(a2, EV.z, dt);                   \
                    dt = __builtin_fmaf(a3, EV.w, dt);                   \
                    OUTV = (xq + dt) + SV;                               \
                } while (0)

            float d0, d1, d2, d3, d4, d5, d6, d7;
            VQ_D(e0, sA.x, d0); VQ_D(e1, sA.y, d1);
            VQ_D(e2, sA.z, d2); VQ_D(e3, sA.w, d3);
            VQ_D(e4, sB.x, d4); VQ_D(e5, sB.y, d5);
            VQ_D(e6, sB.z, d6); VQ_D(e7, sB.w, d7);
            #undef VQ_D

            float m = min3f(dmin[r], d0, d1);
            m = min3f(m, d2, d3);
            m = min3f(m, d4, d5);
            m = min3f(m, d6, d7);
            bg[r] = (m < prev) ? g : bg[r];   // strict <: earliest group ties
            dmin[r] = m;
        }
    }

    // ---- resolution: recompute the 8 winning codes per row from LDS with
    // the identical scalar chain; first bitwise match wins (np.argmin).
    unsigned long long key[RPT];
    #pragma unroll
    for (int r = 0; r < RPT; ++r) {
        const int k0 = kbase + (bg[r] << 3);
        const float a0 = x0[r], a1 = x1[r], a2 = x2c[r], a3 = x3[r];
        const float xq = xs[r];
        int idx = 0x7fffffff;
        #pragma unroll
        for (int h = 0; h < 2; ++h) {
            const float4 sv = sS[(k0 >> 2) + h];
            const float ss[4] = {sv.x, sv.y, sv.z, sv.w};
            #pragma unroll
            for (int j = 0; j < 4; ++j) {
                const int k = k0 + 4 * h + j;
                const float4 e = sE[k];
                float dt = a0 * e.x;
                dt = __builtin_fmaf(a1, e.y, dt);
                dt = __builtin_fmaf(a2, e.z, dt);
                dt = __builtin_fmaf(a3, e.w, dt);
                const float d = (xq + dt) + ss[j];
                idx = min(idx, (d == dmin[r]) ? k : 0x7fffffff);
            }
        }
        // d >= 0 for this data: float bits order-isomorphic as u32; low bits
        // break exact cross-wave ties toward the smaller index.
        key[r] = ((unsigned long long)__float_as_uint(dmin[r]) << 32)
                 | (unsigned)idx;
    }

    // ---- cross-wave reduce: reuse sE's LDS (128 x 17 u64 = 17 KB <= 32 KB) --
    __syncthreads();
    unsigned long long* skey = reinterpret_cast<unsigned long long*>(sE);
    #pragma unroll
    for (int r = 0; r < RPT; ++r)
        skey[(r * 64 + lane) * (KSPLIT + 1) + wid] = key[r];
    __syncthreads();

    if (t < ROWSPB) {
        const int rn = blockIdx.x * ROWSPB + t;
        if (rn < N) {
            unsigned long long k = skey[t * (KSPLIT + 1)];
            #pragma unroll
            for (int s = 1; s < KSPLIT; ++s) {
                unsigned long long v = skey[t * (KSPLIT + 1) + s];
                if (v < k) k = v;
            }
            out[rn] = (int)(unsigned)(k & 0xFFFFFFFFull);
        }
    }
}

extern "C" void kernel_launch(void* const* d_in, const int* in_sizes, int n_in,
                              void* d_out, int out_size, void* d_ws, size_t ws_size,
                              hipStream_t stream) {
    const float* x   = (const float*)d_in[0];   // [16,64,64,4] -> [N,4]
    const float* emb = (const float*)d_in[1];   // [2048,4]
    int* out = (int*)d_out;                     // [N] int32
    const int N = in_sizes[0] / CDIM;           // 65536

    vq_fused<<<(N + ROWSPB - 1) / ROWSPB, TPB, 0, stream>>>(x, emb, out, N);
}

// Round 17
// 27.175 us; speedup vs baseline: 1.6345x; 1.0405x over previous
//
#include <hip/hip_runtime.h>
#include <math.h>

// Bit-match the verified reference fp32 pipeline (rounds 4-16, absmax=0):
//   dot = ascending single-accumulator FMA chain
//   d   = (x2 - 2*dot) + e2, single roundings, strict-< first-occurrence argmin.
// -2 folded into the staged table (exact; verified r14).
//
// r17: the one untested cell — scalar VALU (lean, ~14us) together with RPT=4
// (per-CU uniform-b128 DS traffic halved to ~12.8us). Model (fits r8-r16):
// wall = max(VALU_issue, DS_pipe) where DS = N*K*1.25/(64*RPT) instrs/chip
// at ~12cyc each. KSPLIT=16 + TPB=1024 keeps 16 waves/CU (4/SIMD) hiding.
#pragma clang fp contract(off)

constexpr int KCODES = 2048;   // EMBEDDING_LENGTH
constexpr int CDIM   = 4;      // EMBEDDING_DIM
constexpr int KSPLIT = 16;     // one k-chunk per wave (16 waves/block)
constexpr int KCHUNK = KCODES / KSPLIT;  // 128 codes per wave
constexpr int RPT    = 4;      // rows per lane -> DS/CU = 2560 b128 ~ 12.8us
constexpr int ROWSPB = 64 * RPT;         // 256 rows per block
constexpr int TPB    = 64 * KSPLIT;      // 1024 threads; 1 block/CU

__device__ __forceinline__ float min3f(float a, float b, float c) {
    float d; asm("v_min3_f32 %0, %1, %2, %3" : "=v"(d) : "v"(a), "v"(b), "v"(c)); return d;
}
__device__ __forceinline__ float sumsq(float4 e) {
    // np.sum(e*e, -1): ascending unfused mul-add (n<8 scalar loop)
    return ((e.x * e.x + e.y * e.y) + e.z * e.z) + e.w * e.w;
}

__global__ __launch_bounds__(TPB, 4) void vq_fused(
    const float* __restrict__ x,
    const float* __restrict__ emb,
    int* __restrict__ out,
    int N)
{
    // 40 KB carved: sE (32K, e'=-2e) | sS (8K, sums). skey (34K) reuses base.
    __shared__ char smem[40960];
    float4* sE = reinterpret_cast<float4*>(smem);            // [KCODES]
    float4* sS = reinterpret_cast<float4*>(smem + 32768);    // [KCODES/4]

    const float4* __restrict__ embf4 = reinterpret_cast<const float4*>(emb);
    const int t = threadIdx.x;

    for (int i = t; i < KCODES; i += TPB) {
        float4 e = embf4[i];
        sE[i] = make_float4(-2.0f * e.x, -2.0f * e.y, -2.0f * e.z, -2.0f * e.w);
    }
    for (int q = t; q < KCODES / 4; q += TPB) {
        float4 e0 = embf4[4 * q],     e1 = embf4[4 * q + 1];
        float4 e2 = embf4[4 * q + 2], e3 = embf4[4 * q + 3];
        sS[q] = make_float4(sumsq(e0), sumsq(e1), sumsq(e2), sumsq(e3));
    }
    __syncthreads();

    const int lane = t & 63;
    const int wid   = __builtin_amdgcn_readfirstlane(t >> 6);  // r6 lesson
    const int kbase = wid * KCHUNK;
    const int qbase = kbase >> 2;
    const int nbase = blockIdx.x * ROWSPB + lane;

    float x0[RPT], x1[RPT], x2c[RPT], x3[RPT], xs[RPT];
    float dmin[RPT];
    int   bg[RPT];
    #pragma unroll
    for (int r = 0; r < RPT; ++r) {
        const int n = nbase + r * 64;
        float4 xv = (n < N) ? reinterpret_cast<const float4*>(x)[n]
                            : make_float4(0.f, 0.f, 0.f, 0.f);
        x0[r] = xv.x; x1[r] = xv.y; x2c[r] = xv.z; x3[r] = xv.w;
        xs[r] = ((xv.x * xv.x + xv.y * xv.y) + xv.z * xv.z) + xv.w * xv.w;
        dmin[r] = HUGE_VALF; bg[r] = 0;
    }

    // 6 scalar VALU per code + 1 min3 per 2 codes + 2 tracking per group.
    #pragma unroll 2
    for (int g = 0; g < KCHUNK / 8; ++g) {   // 16 groups x 8 codes
        const int k0 = kbase + (g << 3);
        const float4 e0 = sE[k0 + 0], e1 = sE[k0 + 1];
        const float4 e2 = sE[k0 + 2], e3 = sE[k0 + 3];
        const float4 e4 = sE[k0 + 4], e5 = sE[k0 + 5];
        const float4 e6 = sE[k0 + 6], e7 = sE[k0 + 7];
        const float4 sA = sS[qbase + 2 * g];
        const float4 sB = sS[qbase + 2 * g + 1];

        #pragma unroll
        for (int r = 0; r < RPT; ++r) {
            const float a0 = x0[r], a1 = x1[r], a2 = x2c[r], a3 = x3[r];
            const float xq = xs[r];
            const float prev = dmin[r];

            #define VQ_D(EV, SV, OUTV)                                   \
                do {                                                     \
                    float dt = a0 * EV.x;                                \
                    dt = __builtin_fmaf(a1, EV.y, dt);                   \
                    dt = __builtin_fmaf(a2, EV.z, dt);                   \
                    dt = __builtin_fmaf(a3, EV.w, dt);                   \
                    OUTV = (xq + dt) + SV;                               \
                } while (0)

            float d0, d1, d2, d3, d4, d5, d6, d7;
            VQ_D(e0, sA.x, d0); VQ_D(e1, sA.y, d1);
            VQ_D(e2, sA.z, d2); VQ_D(e3, sA.w, d3);
            VQ_D(e4, sB.x, d4); VQ_D(e5, sB.y, d5);
            VQ_D(e6, sB.z, d6); VQ_D(e7, sB.w, d7);
            #undef VQ_D

            float m = min3f(dmin[r], d0, d1);
            m = min3f(m, d2, d3);
            m = min3f(m, d4, d5);
            m = min3f(m, d6, d7);
            bg[r] = (m < prev) ? g : bg[r];   // strict <: earliest group ties
            dmin[r] = m;
        }
    }

    // ---- resolution: recompute the 8 winning codes per row from LDS with
    // the identical scalar chain; first bitwise match wins (np.argmin).
    unsigned long long key[RPT];
    #pragma unroll
    for (int r = 0; r < RPT; ++r) {
        const int k0 = kbase + (bg[r] << 3);
        const float a0 = x0[r], a1 = x1[r], a2 = x2c[r], a3 = x3[r];
        const float xq = xs[r];
        int idx = 0x7fffffff;
        #pragma unroll
        for (int h = 0; h < 2; ++h) {
            const float4 sv = sS[(k0 >> 2) + h];
            const float ss[4] = {sv.x, sv.y, sv.z, sv.w};
            #pragma unroll
            for (int j = 0; j < 4; ++j) {
                const int k = k0 + 4 * h + j;
                const float4 e = sE[k];
                float dt = a0 * e.x;
                dt = __builtin_fmaf(a1, e.y, dt);
                dt = __builtin_fmaf(a2, e.z, dt);
                dt = __builtin_fmaf(a3, e.w, dt);
                const float d = (xq + dt) + ss[j];
                idx = min(idx, (d == dmin[r]) ? k : 0x7fffffff);
            }
        }
        // d >= 0 for this data: float bits order-isomorphic as u32; low bits
        // break exact cross-wave ties toward the smaller index.
        key[r] = ((unsigned long long)__float_as_uint(dmin[r]) << 32)
                 | (unsigned)idx;
    }

    // ---- cross-wave reduce: reuse smem (256 x 17 u64 = 34 KB <= 40 KB) ----
    __syncthreads();
    unsigned long long* skey = reinterpret_cast<unsigned long long*>(smem);
    #pragma unroll
    for (int r = 0; r < RPT; ++r)
        skey[(r * 64 + lane) * (KSPLIT + 1) + wid] = key[r];
    __syncthreads();

    if (t < ROWSPB) {
        const int rn = blockIdx.x * ROWSPB + t;
        if (rn < N) {
            unsigned long long k = skey[t * (KSPLIT + 1)];
            #pragma unroll
            for (int s = 1; s < KSPLIT; ++s) {
                unsigned long long v = skey[t * (KSPLIT + 1) + s];
                if (v < k) k = v;
            }
            out[rn] = (int)(unsigned)(k & 0xFFFFFFFFull);
        }
    }
}

extern "C" void kernel_launch(void* const* d_in, const int* in_sizes, int n_in,
                              void* d_out, int out_size, void* d_ws, size_t ws_size,
                              hipStream_t stream) {
    const float* x   = (const float*)d_in[0];   // [16,64,64,4] -> [N,4]
    const float* emb = (const float*)d_in[1];   // [2048,4]
    int* out = (int*)d_out;                     // [N] int32
    const int N = in_sizes[0] / CDIM;           // 65536

    vq_fused<<<(N + ROWSPB - 1) / ROWSPB, TPB, 0, stream>>>(x, emb, out, N);
}